// Round 12
// baseline (89.089 us; speedup 1.0000x reference)
//
#include <hip/hip_runtime.h>
#include <math.h>

#define CIN   64
#define COUT  128
#define HW    56
#define L_    3136
#define KTOT  6912
#define TH    8            // tile rows
#define TW    8            // tile cols
#define HALO_W 10
#define NPIX  100          // 10 x 10 halo pixels
#define CSTR  (NPIX*16)    // 1600 B per channel record stripe
#define G8_SIZE (8*CSTR)   // 12800
#define G4_SIZE (4*CSTR)   // 6400
#define BUF_SIZE (G8_SIZE+G4_SIZE) // 19200; x2 dbuf = 38400 B/block

#define BP_BYTES  (COUT * KTOT * 2)       // 1,769,472
#define OUT_BYTES (8 * COUT * L_ * 4)     // 12,845,056
// split layout
#define P1_OFF    BP_BYTES
#define PARTS_OFF (P1_OFF + OUT_BYTES)
#define SSS_OFF   (PARTS_OFF + 2048 * 4)
#define WS_NEEDED (SSS_OFF + 1024 * 4)
// fallback (no-split) layout
#define PARTF_OFF BP_BYTES
#define SSF_OFF   (PARTF_OFF + 2048 * 4)

typedef __attribute__((ext_vector_type(8))) short bf16x8;
typedef __attribute__((ext_vector_type(4))) float f32x4;
typedef unsigned long long u64;

#define BLOAD(dst, addr) \
    asm volatile("global_load_dwordx4 %0, %1, off" : "=v"(dst) : "v"(addr))
#define XLOAD(dst, addr) \
    asm volatile("global_load_dword %0, %1, off" : "=v"(dst) : "v"(addr))

__device__ __forceinline__ unsigned short f2bf(float f) {
    unsigned int u = __float_as_uint(f);
    return (unsigned short)((u + 0x7FFFu + ((u >> 16) & 1u)) >> 16);   // RNE
}
__device__ __forceinline__ unsigned int pk2(float a, float b) {
    return (unsigned int)f2bf(a) | ((unsigned int)f2bf(b) << 16);
}

// Reference basis for one pixel. g8rec built in registers, ONE b128 write;
// g4half (8B) = {f8, f9, f10, raw x}.
__device__ __forceinline__ void eval_store(float xv, char* g8rec, char* g4half) {
    float u  = 1.0f / (1.0f + __expf(-xv));
    float tt = u * 11.0f;
    int s = (int)floorf(tt);
    s = (s > 10) ? 10 : s;
    float xf  = tt - (float)s;
    float x2  = xf * xf, x3 = x2 * xf;
    float omx = 1.0f - xf;
    const float i6 = 1.0f / 6.0f;
    float w3 = x3 * i6;
    float w2 = fmaf(fmaf(fmaf(-3.0f, xf, 3.0f), xf, 3.0f), xf, 1.0f) * i6;
    float w1 = fmaf(fmaf(3.0f, xf, -6.0f), x2, 4.0f) * i6;
    float w0 = omx * omx * omx * i6;

    unsigned int b0 = f2bf(w0), b1 = f2bf(w1), b2 = f2bf(w2), b3 = f2bf(w3);
    unsigned int slot[8];
#pragma unroll
    for (int j = 0; j < 8; j++) {
        unsigned int v = 0;
        v = (s == j)     ? b3 : v;
        v = (s == j + 1) ? b2 : v;
        v = (s == j + 2) ? b1 : v;
        v = (s == j + 3) ? b0 : v;
        slot[j] = v;
    }
    uint4 rec;
    rec.x = slot[0] | (slot[1] << 16);
    rec.y = slot[2] | (slot[3] << 16);
    rec.z = slot[4] | (slot[5] << 16);
    rec.w = slot[6] | (slot[7] << 16);
    *reinterpret_cast<uint4*>(g8rec) = rec;

    float y = tt - 8.0f;
    float f8 = 0.0f;
    f8 = (s == 8)  ? 0.5f * y * y : f8;
    f8 = (s == 9)  ? 0.5f * fmaf(-2.0f * y, y, fmaf(6.0f, y, -3.0f)) : f8;
    f8 = (s == 10) ? 0.5f * (3.0f - y) * (3.0f - y) : f8;
    float z = tt - 9.0f;
    float f9 = 0.0f;
    f9 = (s == 9)  ? z : f9;
    f9 = (s == 10) ? 2.0f - z : f9;
    float f10 = (s == 10) ? 1.0f : 0.0f;
    *reinterpret_cast<uint2*>(g4half) = make_uint2(pk2(f8, f9), pk2(f10, xv));
}

// Pack B in DENSE per-(kstep,o) 64B units: Bp[kstep][o][e32] (same as R6-R11).
__global__ __launch_bounds__(256) void k_packB(const float* __restrict__ cp,
                                               const float* __restrict__ w,
                                               unsigned short* __restrict__ Bp) {
    int idx = blockIdx.x * 256 + threadIdx.x;
    if (idx >= COUT * KTOT) return;
    int kstep = idx >> 12;
    int rem   = idx & 4095;
    int o     = rem >> 5;
    int e32   = rem & 31;
    int ch = kstep / 27, sc = kstep - ch * 27;
    int ktap = sc / 3, ph = sc - ktap * 3;
    int c, n;
    if (ph < 2) { c = ch * 8 + ph * 4 + (e32 >> 3); n = e32 & 7; }
    else        { int sub = e32 & 7; c = ch * 8 + (e32 >> 3) * 2 + (sub >> 2); n = 8 + (sub & 3); }
    float v;
    if (n < 11) v = cp[(((size_t)o * CIN + c) * 9 + ktap) * 11 + n];
    else        v = w[((size_t)o * CIN + c) * 9 + ktap];
    Bp[idx] = f2bf(v);
}

// GEMM. ksplit=1: grid 784, block=(tile,kh); kh handles 4 chunks (32 ch),
// kh=0 -> dst0(out), kh=1 -> dst1(ws partial). ksplit=0: grid 392, full K.
// Bias omitted (cancels exactly in BN; conv_b is zeros anyway).
__global__ __launch_bounds__(256, 2) void k_main(const float* __restrict__ x,
                                                 const unsigned short* __restrict__ Bp,
                                                 float* __restrict__ dst0,
                                                 float* __restrict__ dst1,
                                                 int ksplit) {
    __shared__ char lds[2 * BUF_SIZE];

    const int bid  = blockIdx.x;
    const int kh   = ksplit ? (bid & 1) : 0;
    const int tb   = ksplit ? (bid >> 1) : bid;
    const int nch  = ksplit ? 4 : 8;
    float* dst     = kh ? dst1 : dst0;

    const int b    = tb / 49;
    const int tile = tb - b * 49;
    const int th   = tile / 7;
    const int tw   = tile - th * 7;
    const int t    = threadIdx.x;
    const int lane = t & 63;
    const int wid  = t >> 6;              // 0..3 : o-quarter

    // ---- staging roles: 800 (pixel,channel) pairs per chunk, 4 slots/thread
    const bool valid = (t < 200);
    const int p     = (t < 100) ? t : (t - 100);
    const int hi100 = (t >= 100) ? 1 : 0;
    const int ph_  = p / 10, pw_ = p - ph_ * 10;
    const int hg = th * TH - 1 + ph_;
    const int wg = tw * TW - 1 + pw_;
    const bool inb = valid && (hg >= 0) && (hg < HW) && (wg >= 0) && (wg < HW);
    const u64 xadv = inb ? (u64)8 * L_ * 4 : 0;
    u64 px[4];
#pragma unroll
    for (int r = 0; r < 4; r++) {
        int c0 = kh * 32 + 2 * r + hi100;
        px[r] = inb ? ((u64)x + (((u64)b * CIN + c0) * L_ + (u64)hg * HW + wg) * 4)
                    : (u64)x;
    }

    // ---- MFMA lane invariants ----
    const int q   = lane >> 4;
    const int r15 = lane & 15;
    int P[4];
#pragma unroll
    for (int mi = 0; mi < 4; mi++) {
        int lh = mi * 2 + (r15 >> 3);
        int lw = r15 & 7;
        P[mi] = (lh * HALO_W + lw) * 16 + q * CSTR;
    }
    const int obase = wid * 32 + r15;

    // B running pointers, dense layout; start at this half's ksteps.
    const u64 bend = (u64)Bp + BP_BYTES;
    u64 pa0 = (u64)Bp + (u64)kh * 108 * 8192 + ((u64)obase * 64) + ((u64)q * 16);
    u64 pa1 = pa0 + 1024;                 // +16 o

    f32x4 acc[4][2];
#pragma unroll
    for (int mi = 0; mi < 4; mi++)
#pragma unroll
        for (int ni = 0; ni < 2; ni++) acc[mi][ni] = (f32x4){0.f, 0.f, 0.f, 0.f};

    // ---- chunk-0 x loads + eval ----
    float xa[4];
    XLOAD(xa[0], px[0]); XLOAD(xa[1], px[1]);
    XLOAD(xa[2], px[2]); XLOAD(xa[3], px[3]);
#pragma unroll
    for (int r = 0; r < 4; r++) px[r] += xadv;   // -> chunk-1 channels
    asm volatile("s_waitcnt vmcnt(0)");
    __builtin_amdgcn_sched_barrier(0);
    if (valid) {
#pragma unroll
        for (int r = 0; r < 4; r++) {
            float va = inb ? xa[r] : 0.0f;
            int c = 2 * r + hi100;
            eval_store(va, &lds[c * CSTR + p * 16],
                       &lds[G8_SIZE + r * CSTR + p * 16 + hi100 * 8]);
        }
    }
    __syncthreads();

    // ---- B pipeline prologue: 9 pairs in flight ----
    bf16x8 breg0[9], breg1[9];
#pragma unroll
    for (int s = 0; s < 9; s++) {
        BLOAD(breg0[s], pa0);
        BLOAD(breg1[s], pa1);
        pa0 += 8192; pa1 += 8192;
    }

#pragma unroll 1
    for (int cr = 0; cr < nch; cr++) {
        // x quad for chunk cr+1 (last chunk: dummy reload, in bounds, unused)
        XLOAD(xa[0], px[0]); XLOAD(xa[1], px[1]);
        XLOAD(xa[2], px[2]); XLOAD(xa[3], px[3]);
        if (cr < nch - 2) {
#pragma unroll
            for (int r = 0; r < 4; r++) px[r] += xadv;
        }

        char* abuf = &lds[(cr & 1) * BUF_SIZE];
        char* nbuf = &lds[((cr + 1) & 1) * BUF_SIZE];

        bf16x8 areg[2][4];
        auto aread = [&](int s, bf16x8 (&a)[4]) {
            int k = s / 3, bp = s - k * 3;
            int ki = k / 3, kj = k - ki * 3;
            int poff = (ki * HALO_W + kj) * 16;
            int aoff = (bp == 2) ? (G8_SIZE + poff) : (bp * 4 * CSTR + poff);
#pragma unroll
            for (int mi = 0; mi < 4; mi++)
                a[mi] = *reinterpret_cast<const bf16x8*>(abuf + P[mi] + aoff);
        };
        aread(0, areg[0]);

#pragma unroll
        for (int s = 0; s < 27; s++) {
            if (s + 1 < 27) aread(s + 1, areg[(s + 1) & 1]);
            // Post-drain queue: outstanding = 4 + 2s at this wait; vmcnt(16)
            // retires the consumed pair with margin, and the x quad by s==8
            // (before the eval below).
            asm volatile("s_waitcnt vmcnt(16)");
            __builtin_amdgcn_sched_barrier(0);
            const int bs = s % 9;
#pragma unroll
            for (int mi = 0; mi < 4; mi++) {
                acc[mi][0] = __builtin_amdgcn_mfma_f32_16x16x32_bf16(areg[s & 1][mi], breg0[bs], acc[mi][0], 0, 0, 0);
                acc[mi][1] = __builtin_amdgcn_mfma_f32_16x16x32_bf16(areg[s & 1][mi], breg1[bs], acc[mi][1], 0, 0, 0);
            }
            // refill consumed slot (wraps past Bp end -> start; wrapped values
            // never consumed)
            BLOAD(breg0[bs], pa0);
            BLOAD(breg1[bs], pa1);
            pa0 += 8192; if (pa0 >= bend) pa0 -= BP_BYTES;
            pa1 += 8192; if (pa1 >= bend) pa1 -= BP_BYTES;
        }

        if (cr < nch - 1 && valid) {
#pragma unroll
            for (int r = 0; r < 4; r++) {
                float va = inb ? xa[r] : 0.0f;
                int c = 2 * r + hi100;
                eval_store(va, &nbuf[c * CSTR + p * 16],
                           &nbuf[G8_SIZE + r * CSTR + p * 16 + hi100 * 8]);
            }
        }
        __syncthreads();   // full fence: drains vmem+lds, orders LDS reuse
    }

    asm volatile("s_waitcnt vmcnt(0)");   // drain tail prefetches
    __builtin_amdgcn_sched_barrier(0);

    // ---- epilogue: plain float4 store of this K-range's partial ----
#pragma unroll
    for (int ni = 0; ni < 2; ni++) {
        int o = obase + ni * 16;
#pragma unroll
        for (int mi = 0; mi < 4; mi++) {
            int lh = mi * 2 + (q >> 1);
            int lw0 = (q & 1) * 4;
            int lg = (th * TH + lh) * HW + tw * TW + lw0;
            float4 v;
            v.x = acc[mi][ni][0];
            v.y = acc[mi][ni][1];
            v.z = acc[mi][ni][2];
            v.w = acc[mi][ni][3];
            *reinterpret_cast<float4*>(&dst[(size_t)(b * COUT + o) * L_ + lg]) = v;
        }
    }
}

// Partial sums per (b,o) slab; optionally combines s0+s1 on the fly.
__global__ __launch_bounds__(256) void k_part(const float* __restrict__ s0,
                                              const float* __restrict__ s1,
                                              float* __restrict__ part,
                                              int split) {
    const int slab = blockIdx.x;
    const float4* p0 = reinterpret_cast<const float4*>(s0 + (size_t)slab * L_);
    const float4* p1 = reinterpret_cast<const float4*>(s1 + (size_t)slab * L_);
    const int t = threadIdx.x;
    float sum = 0.f, sq = 0.f;
    if (split) {
        for (int i = t; i < L_ / 4; i += 256) {
            float4 a = p0[i], c = p1[i];
            float vx = a.x + c.x, vy = a.y + c.y, vz = a.z + c.z, vw = a.w + c.w;
            sum += vx + vy + vz + vw;
            sq  += vx * vx + vy * vy + vz * vz + vw * vw;
        }
    } else {
        for (int i = t; i < L_ / 4; i += 256) {
            float4 a = p0[i];
            sum += a.x + a.y + a.z + a.w;
            sq  += a.x * a.x + a.y * a.y + a.z * a.z + a.w * a.w;
        }
    }
    __shared__ float rs[256], rq[256];
    rs[t] = sum; rq[t] = sq;
    __syncthreads();
    for (int off = 128; off > 0; off >>= 1) {
        if (t < off) { rs[t] += rs[t + off]; rq[t] += rq[t + off]; }
        __syncthreads();
    }
    if (t == 0) { part[slab] = rs[0]; part[1024 + slab] = rq[0]; }
}

__global__ __launch_bounds__(128) void k_final(const float* __restrict__ part,
                                               const float* __restrict__ gamma,
                                               const float* __restrict__ beta,
                                               float* __restrict__ ss) {
    int o = threadIdx.x;
    float sum = 0.f, sq = 0.f;
#pragma unroll
    for (int b = 0; b < 8; b++) {
        sum += part[b * COUT + o];
        sq  += part[1024 + b * COUT + o];
    }
    float n = (float)(8 * L_);
    float mean = sum / n;
    float var  = sq / n - mean * mean;
    float scale = gamma[o] * rsqrtf(var + 1e-5f);
    ss[o]        = scale;
    ss[COUT + o] = beta[o] - mean * scale;
}

// Normalize; optionally combines out+part1 on the fly.
__global__ __launch_bounds__(256) void k_norm(float* __restrict__ out,
                                              const float* __restrict__ p1,
                                              const float* __restrict__ ss,
                                              int split) {
    const int n4 = 8 * COUT * L_ / 4;
    for (int i = blockIdx.x * 256 + threadIdx.x; i < n4; i += gridDim.x * 256) {
        int o = ((i * 4) / L_) & (COUT - 1);
        float sc = ss[o], sh = ss[COUT + o];
        float4 v = reinterpret_cast<const float4*>(out)[i];
        if (split) {
            float4 w = reinterpret_cast<const float4*>(p1)[i];
            v.x += w.x; v.y += w.y; v.z += w.z; v.w += w.w;
        }
        v.x = fmaf(v.x, sc, sh);
        v.y = fmaf(v.y, sc, sh);
        v.z = fmaf(v.z, sc, sh);
        v.w = fmaf(v.w, sc, sh);
        reinterpret_cast<float4*>(out)[i] = v;
    }
}

extern "C" void kernel_launch(void* const* d_in, const int* in_sizes, int n_in,
                              void* d_out, int out_size, void* d_ws, size_t ws_size,
                              hipStream_t stream) {
    const float* x     = (const float*)d_in[0];
    const float* cp    = (const float*)d_in[1];
    const float* w     = (const float*)d_in[2];
    const float* gamma = (const float*)d_in[4];
    const float* beta  = (const float*)d_in[5];
    float* out = (float*)d_out;

    const int split = (ws_size >= (size_t)WS_NEEDED) ? 1 : 0;

    unsigned short* Bp = (unsigned short*)d_ws;
    float* p1   = (float*)((char*)d_ws + P1_OFF);
    float* part = (float*)((char*)d_ws + (split ? PARTS_OFF : PARTF_OFF));
    float* ss   = (float*)((char*)d_ws + (split ? SSS_OFF : SSF_OFF));

    k_packB<<<(COUT * KTOT + 255) / 256, 256, 0, stream>>>(cp, w, Bp);
    k_main<<<split ? 784 : 392, 256, 0, stream>>>(x, Bp, out, p1, split);
    k_part<<<1024, 256, 0, stream>>>(out, p1, part, split);
    k_final<<<1, 128, 0, stream>>>(part, gamma, beta, ss);
    k_norm<<<2048, 256, 0, stream>>>(out, p1, ss, split);
}

// Round 15
// 83.194 us; speedup vs baseline: 1.0709x; 1.0709x over previous
//
#include <hip/hip_runtime.h>
#include <math.h>

#define CIN   64
#define COUT  128
#define HW    56
#define L_    3136
#define KTOT  6912
#define TH    8            // tile rows
#define TW    8            // tile cols
#define HALO_W 10
#define NPIX  100          // 10 x 10 halo pixels
#define CSTR  (NPIX*16 + 32)  // 1632 B stride (R11-proven)
#define G8_SIZE (8*CSTR)   // 13056
#define G4_SIZE (4*CSTR)   // 6528
#define BUF_SIZE (G8_SIZE+G4_SIZE) // 19584; x2 dbuf = 39168 B/block

#define BP_BYTES (COUT * KTOT * 2)        // 1,769,472
#define PART_OFF BP_BYTES
#define SS_OFF   (PART_OFF + 2048 * 4)

typedef __attribute__((ext_vector_type(8))) short bf16x8;
typedef __attribute__((ext_vector_type(4))) float f32x4;
typedef unsigned long long u64;

#define BLOAD(dst, addr) \
    asm volatile("global_load_dwordx4 %0, %1, off" : "=v"(dst) : "v"(addr))
#define XLOAD(dst, addr) \
    asm volatile("global_load_dword %0, %1, off" : "=v"(dst) : "v"(addr))

__device__ __forceinline__ unsigned short f2bf(float f) {
    unsigned int u = __float_as_uint(f);
    return (unsigned short)((u + 0x7FFFu + ((u >> 16) & 1u)) >> 16);   // RNE
}
__device__ __forceinline__ unsigned int pk2(float a, float b) {
    return (unsigned int)f2bf(a) | ((unsigned int)f2bf(b) << 16);
}

// Reference basis for one pixel. g8rec built in registers, ONE b128 write;
// g4half (8B) = {f8, f9, f10, raw x}.
__device__ __forceinline__ void eval_store(float xv, char* g8rec, char* g4half) {
    float u  = 1.0f / (1.0f + __expf(-xv));
    float tt = u * 11.0f;
    int s = (int)floorf(tt);
    s = (s > 10) ? 10 : s;
    float xf  = tt - (float)s;
    float x2  = xf * xf, x3 = x2 * xf;
    float omx = 1.0f - xf;
    const float i6 = 1.0f / 6.0f;
    float w3 = x3 * i6;
    float w2 = fmaf(fmaf(fmaf(-3.0f, xf, 3.0f), xf, 3.0f), xf, 1.0f) * i6;
    float w1 = fmaf(fmaf(3.0f, xf, -6.0f), x2, 4.0f) * i6;
    float w0 = omx * omx * omx * i6;

    unsigned int b0 = f2bf(w0), b1 = f2bf(w1), b2 = f2bf(w2), b3 = f2bf(w3);
    unsigned int slot[8];
#pragma unroll
    for (int j = 0; j < 8; j++) {
        unsigned int v = 0;
        v = (s == j)     ? b3 : v;
        v = (s == j + 1) ? b2 : v;
        v = (s == j + 2) ? b1 : v;
        v = (s == j + 3) ? b0 : v;
        slot[j] = v;
    }
    uint4 rec;
    rec.x = slot[0] | (slot[1] << 16);
    rec.y = slot[2] | (slot[3] << 16);
    rec.z = slot[4] | (slot[5] << 16);
    rec.w = slot[6] | (slot[7] << 16);
    *reinterpret_cast<uint4*>(g8rec) = rec;

    float y = tt - 8.0f;
    float f8 = 0.0f;
    f8 = (s == 8)  ? 0.5f * y * y : f8;
    f8 = (s == 9)  ? 0.5f * fmaf(-2.0f * y, y, fmaf(6.0f, y, -3.0f)) : f8;
    f8 = (s == 10) ? 0.5f * (3.0f - y) * (3.0f - y) : f8;
    float z = tt - 9.0f;
    float f9 = 0.0f;
    f9 = (s == 9)  ? z : f9;
    f9 = (s == 10) ? 2.0f - z : f9;
    float f10 = (s == 10) ? 1.0f : 0.0f;
    *reinterpret_cast<uint2*>(g4half) = make_uint2(pk2(f8, f9), pk2(f10, xv));
}

// Pack B in DENSE per-(kstep,o) 64B units: Bp[kstep][o][e32] (same as R6-R14).
__global__ __launch_bounds__(256) void k_packB(const float* __restrict__ cp,
                                               const float* __restrict__ w,
                                               unsigned short* __restrict__ Bp) {
    int idx = blockIdx.x * 256 + threadIdx.x;
    if (idx >= COUT * KTOT) return;
    int kstep = idx >> 12;
    int rem   = idx & 4095;
    int o     = rem >> 5;
    int e32   = rem & 31;
    int ch = kstep / 27, sc = kstep - ch * 27;
    int ktap = sc / 3, ph = sc - ktap * 3;
    int c, n;
    if (ph < 2) { c = ch * 8 + ph * 4 + (e32 >> 3); n = e32 & 7; }
    else        { int sub = e32 & 7; c = ch * 8 + (e32 >> 3) * 2 + (sub >> 2); n = 8 + (sub & 3); }
    float v;
    if (n < 11) v = cp[(((size_t)o * CIN + c) * 9 + ktap) * 11 + n];
    else        v = w[((size_t)o * CIN + c) * 9 + ktap];
    Bp[idx] = f2bf(v);
}

// R11-proven full-K GEMM + XCD-swizzled block mapping + fused BN-stats
// epilogue (shfl-reduce + 4 atomicAdds per lane-group). Bias omitted
// (cancels exactly in BN; conv_b is zeros anyway).
__global__ __launch_bounds__(256) void k_main(const float* __restrict__ x,
                                              const unsigned short* __restrict__ Bp,
                                              float* __restrict__ out,
                                              float* __restrict__ part) {
    __shared__ char lds[2 * BUF_SIZE];

    const int bid  = blockIdx.x;
    // XCD swizzle: 392 = 8*49; one image per XCD -> x+B L2-resident.
    const int b    = bid & 7;
    const int tile = bid >> 3;            // 0..48
    const int th   = tile / 7;
    const int tw   = tile - th * 7;
    const int t    = threadIdx.x;
    const int lane = t & 63;
    const int wid  = t >> 6;              // 0..3 : o-quarter

    // ---- staging roles: 800 (pixel,channel) pairs per chunk, 4 slots/thread
    const bool valid = (t < 200);
    const int p     = (t < 100) ? t : (t - 100);
    const int hi100 = (t >= 100) ? 1 : 0;
    const int ph_  = p / 10, pw_ = p - ph_ * 10;
    const int hg = th * TH - 1 + ph_;
    const int wg = tw * TW - 1 + pw_;
    const bool inb = valid && (hg >= 0) && (hg < HW) && (wg >= 0) && (wg < HW);
    const u64 xadv = inb ? (u64)8 * L_ * 4 : 0;
    u64 px[4];
#pragma unroll
    for (int r = 0; r < 4; r++) {
        int c0 = 2 * r + hi100;
        px[r] = inb ? ((u64)x + (((u64)b * CIN + c0) * L_ + (u64)hg * HW + wg) * 4)
                    : (u64)x;
    }

    // ---- MFMA lane invariants ----
    const int q   = lane >> 4;
    const int r15 = lane & 15;
    int P[4];
#pragma unroll
    for (int mi = 0; mi < 4; mi++) {
        int lh = mi * 2 + (r15 >> 3);
        int lw = r15 & 7;
        P[mi] = (lh * HALO_W + lw) * 16 + q * CSTR;
    }
    const int obase = wid * 32 + r15;

    // B running pointers, dense layout; per-step stride 8192B, wrap at end.
    const u64 bend = (u64)Bp + BP_BYTES;
    u64 pa0 = (u64)Bp + ((u64)obase * 64) + ((u64)q * 16);
    u64 pa1 = pa0 + 1024;                 // +16 o

    f32x4 acc[4][2];
#pragma unroll
    for (int mi = 0; mi < 4; mi++)
#pragma unroll
        for (int ni = 0; ni < 2; ni++) acc[mi][ni] = (f32x4){0.f, 0.f, 0.f, 0.f};

    // ---- chunk-0 x loads + eval ----
    float xa[4];
    XLOAD(xa[0], px[0]); XLOAD(xa[1], px[1]);
    XLOAD(xa[2], px[2]); XLOAD(xa[3], px[3]);
#pragma unroll
    for (int r = 0; r < 4; r++) px[r] += xadv;   // -> chunk-1 channels
    asm volatile("s_waitcnt vmcnt(0)");
    __builtin_amdgcn_sched_barrier(0);
    if (valid) {
#pragma unroll
        for (int r = 0; r < 4; r++) {
            float va = inb ? xa[r] : 0.0f;
            int c = 2 * r + hi100;
            eval_store(va, &lds[c * CSTR + p * 16],
                       &lds[G8_SIZE + r * CSTR + p * 16 + hi100 * 8]);
        }
    }
    __syncthreads();

    // ---- B pipeline prologue: 9 pairs in flight ----
    bf16x8 breg0[9], breg1[9];
#pragma unroll
    for (int s = 0; s < 9; s++) {
        BLOAD(breg0[s], pa0);
        BLOAD(breg1[s], pa1);
        pa0 += 8192; pa1 += 8192;
    }

#pragma unroll 1
    for (int ch = 0; ch < 8; ch++) {
        // x quad for chunk ch+1 (ch==7: dummy reload of chunk-7, in bounds)
        XLOAD(xa[0], px[0]); XLOAD(xa[1], px[1]);
        XLOAD(xa[2], px[2]); XLOAD(xa[3], px[3]);
        if (ch < 6) {                      // keep px in bounds for dummy reload
#pragma unroll
            for (int r = 0; r < 4; r++) px[r] += xadv;
        }

        char* abuf = &lds[(ch & 1) * BUF_SIZE];
        char* nbuf = &lds[((ch + 1) & 1) * BUF_SIZE];

        bf16x8 areg[3][4];
        auto aread = [&](int s, bf16x8 (&a)[4]) {
            int k = s / 3, bp = s - k * 3;
            int ki = k / 3, kj = k - ki * 3;
            int poff = (ki * HALO_W + kj) * 16;
            int aoff = (bp == 2) ? (G8_SIZE + poff) : (bp * 4 * CSTR + poff);
#pragma unroll
            for (int mi = 0; mi < 4; mi++)
                a[mi] = *reinterpret_cast<const bf16x8*>(abuf + P[mi] + aoff);
        };
        aread(0, areg[0]);
        aread(1, areg[1]);

#pragma unroll
        for (int s = 0; s < 27; s++) {
            if (s + 2 < 27) aread(s + 2, areg[(s + 2) % 3]);
            // Post-drain queue: outstanding = 4 + 2s (+prologue on ch==0);
            // vmcnt(16) always retires the consumed pair, and the x quad by
            // s==8 (before the eval below).
            asm volatile("s_waitcnt vmcnt(16)");
            __builtin_amdgcn_sched_barrier(0);
            const int bs = s % 9;
#pragma unroll
            for (int mi = 0; mi < 4; mi++) {
                acc[mi][0] = __builtin_amdgcn_mfma_f32_16x16x32_bf16(areg[s % 3][mi], breg0[bs], acc[mi][0], 0, 0, 0);
                acc[mi][1] = __builtin_amdgcn_mfma_f32_16x16x32_bf16(areg[s % 3][mi], breg1[bs], acc[mi][1], 0, 0, 0);
            }
            // refill consumed slot (wraps past Bp end -> start; wrapped values
            // never consumed)
            BLOAD(breg0[bs], pa0);
            BLOAD(breg1[bs], pa1);
            pa0 += 8192; if (pa0 >= bend) pa0 -= BP_BYTES;
            pa1 += 8192; if (pa1 >= bend) pa1 -= BP_BYTES;
        }

        if (ch < 7 && valid) {
#pragma unroll
            for (int r = 0; r < 4; r++) {
                float va = inb ? xa[r] : 0.0f;
                int c = 2 * r + hi100;
                eval_store(va, &nbuf[c * CSTR + p * 16],
                           &nbuf[G8_SIZE + r * CSTR + p * 16 + hi100 * 8]);
            }
        }
        __syncthreads();   // full fence: drains vmem+lds, orders LDS reuse
    }

    // ---- epilogue: store + fused BN partial stats ----
    float psum[2] = {0.f, 0.f}, psq[2] = {0.f, 0.f};
#pragma unroll
    for (int ni = 0; ni < 2; ni++) {
        int o = obase + ni * 16;
#pragma unroll
        for (int mi = 0; mi < 4; mi++) {
            int lh = mi * 2 + (q >> 1);
            int lw0 = (q & 1) * 4;
            int lg = (th * TH + lh) * HW + tw * TW + lw0;
            float4 v;
            v.x = acc[mi][ni][0];
            v.y = acc[mi][ni][1];
            v.z = acc[mi][ni][2];
            v.w = acc[mi][ni][3];
            *reinterpret_cast<float4*>(&out[(size_t)(b * COUT + o) * L_ + lg]) = v;
            psum[ni] += v.x + v.y + v.z + v.w;
            psq[ni]  += v.x * v.x + v.y * v.y + v.z * v.z + v.w * v.w;
        }
    }
    // reduce across the 4 q-groups (lanes r15, r15+16, r15+32, r15+48 share o)
#pragma unroll
    for (int ni = 0; ni < 2; ni++) {
        psum[ni] += __shfl_xor(psum[ni], 16);
        psum[ni] += __shfl_xor(psum[ni], 32);
        psq[ni]  += __shfl_xor(psq[ni], 16);
        psq[ni]  += __shfl_xor(psq[ni], 32);
    }
    if (q == 0) {
#pragma unroll
        for (int ni = 0; ni < 2; ni++) {
            int o = obase + ni * 16;
            atomicAdd(&part[b * COUT + o], psum[ni]);
            atomicAdd(&part[1024 + b * COUT + o], psq[ni]);
        }
    }
}

__global__ __launch_bounds__(128) void k_final(const float* __restrict__ part,
                                               const float* __restrict__ gamma,
                                               const float* __restrict__ beta,
                                               float* __restrict__ ss) {
    int o = threadIdx.x;
    float sum = 0.f, sq = 0.f;
#pragma unroll
    for (int b = 0; b < 8; b++) {
        sum += part[b * COUT + o];
        sq  += part[1024 + b * COUT + o];
    }
    float n = (float)(8 * L_);
    float mean = sum / n;
    float var  = sq / n - mean * mean;
    float scale = gamma[o] * rsqrtf(var + 1e-5f);
    ss[o]        = scale;
    ss[COUT + o] = beta[o] - mean * scale;
}

__global__ __launch_bounds__(256) void k_norm(float* __restrict__ out,
                                              const float* __restrict__ ss) {
    const int n4 = 8 * COUT * L_ / 4;
    for (int i = blockIdx.x * 256 + threadIdx.x; i < n4; i += gridDim.x * 256) {
        int o = ((i * 4) / L_) & (COUT - 1);
        float sc = ss[o], sh = ss[COUT + o];
        float4 v = reinterpret_cast<float4*>(out)[i];
        v.x = fmaf(v.x, sc, sh);
        v.y = fmaf(v.y, sc, sh);
        v.z = fmaf(v.z, sc, sh);
        v.w = fmaf(v.w, sc, sh);
        reinterpret_cast<float4*>(out)[i] = v;
    }
}

extern "C" void kernel_launch(void* const* d_in, const int* in_sizes, int n_in,
                              void* d_out, int out_size, void* d_ws, size_t ws_size,
                              hipStream_t stream) {
    const float* x     = (const float*)d_in[0];
    const float* cp    = (const float*)d_in[1];
    const float* w     = (const float*)d_in[2];
    const float* gamma = (const float*)d_in[4];
    const float* beta  = (const float*)d_in[5];
    float* out = (float*)d_out;

    unsigned short* Bp = (unsigned short*)d_ws;
    float* part = (float*)((char*)d_ws + PART_OFF);
    float* ss   = (float*)((char*)d_ws + SS_OFF);

    hipMemsetAsync(part, 0, 2048 * sizeof(float), stream);
    k_packB<<<(COUT * KTOT + 255) / 256, 256, 0, stream>>>(cp, w, Bp);
    k_main<<<8 * 49, 256, 0, stream>>>(x, Bp, out, part);
    k_final<<<1, 128, 0, stream>>>(part, gamma, beta, ss);
    k_norm<<<2048, 256, 0, stream>>>(out, ss);
}

// Round 16
// 82.922 us; speedup vs baseline: 1.0744x; 1.0033x over previous
//
#include <hip/hip_runtime.h>
#include <math.h>

#define CIN   64
#define COUT  128
#define HW    56
#define L_    3136
#define KTOT  6912
#define TH    8            // tile rows
#define TW    8            // tile cols
#define HALO_W 10
#define NPIX  100          // 10 x 10 halo pixels
#define CSTR  (NPIX*16 + 32)  // 1632 B stride (R11-proven)
#define G8_SIZE (8*CSTR)   // 13056
#define G4_SIZE (4*CSTR)   // 6528
#define BUF_SIZE (G8_SIZE+G4_SIZE) // 19584; x2 dbuf = 39168 B/block

#define BP_BYTES (COUT * KTOT * 2)        // 1,769,472
#define PART_OFF BP_BYTES
#define SS_OFF   (PART_OFF + 2048 * 4)

typedef __attribute__((ext_vector_type(8))) short bf16x8;
typedef __attribute__((ext_vector_type(4))) float f32x4;
typedef unsigned long long u64;

#define BLOAD(dst, addr) \
    asm volatile("global_load_dwordx4 %0, %1, off" : "=v"(dst) : "v"(addr))
#define XLOAD(dst, addr) \
    asm volatile("global_load_dword %0, %1, off" : "=v"(dst) : "v"(addr))

__device__ __forceinline__ unsigned short f2bf(float f) {
    unsigned int u = __float_as_uint(f);
    return (unsigned short)((u + 0x7FFFu + ((u >> 16) & 1u)) >> 16);   // RNE
}
__device__ __forceinline__ unsigned int pk2(float a, float b) {
    return (unsigned int)f2bf(a) | ((unsigned int)f2bf(b) << 16);
}

// Reference basis for one pixel. g8rec built in registers, ONE b128 write;
// g4half (8B) = {f8, f9, f10, raw x}.
__device__ __forceinline__ void eval_store(float xv, char* g8rec, char* g4half) {
    float u  = 1.0f / (1.0f + __expf(-xv));
    float tt = u * 11.0f;
    int s = (int)floorf(tt);
    s = (s > 10) ? 10 : s;
    float xf  = tt - (float)s;
    float x2  = xf * xf, x3 = x2 * xf;
    float omx = 1.0f - xf;
    const float i6 = 1.0f / 6.0f;
    float w3 = x3 * i6;
    float w2 = fmaf(fmaf(fmaf(-3.0f, xf, 3.0f), xf, 3.0f), xf, 1.0f) * i6;
    float w1 = fmaf(fmaf(3.0f, xf, -6.0f), x2, 4.0f) * i6;
    float w0 = omx * omx * omx * i6;

    unsigned int b0 = f2bf(w0), b1 = f2bf(w1), b2 = f2bf(w2), b3 = f2bf(w3);
    unsigned int slot[8];
#pragma unroll
    for (int j = 0; j < 8; j++) {
        unsigned int v = 0;
        v = (s == j)     ? b3 : v;
        v = (s == j + 1) ? b2 : v;
        v = (s == j + 2) ? b1 : v;
        v = (s == j + 3) ? b0 : v;
        slot[j] = v;
    }
    uint4 rec;
    rec.x = slot[0] | (slot[1] << 16);
    rec.y = slot[2] | (slot[3] << 16);
    rec.z = slot[4] | (slot[5] << 16);
    rec.w = slot[6] | (slot[7] << 16);
    *reinterpret_cast<uint4*>(g8rec) = rec;

    float y = tt - 8.0f;
    float f8 = 0.0f;
    f8 = (s == 8)  ? 0.5f * y * y : f8;
    f8 = (s == 9)  ? 0.5f * fmaf(-2.0f * y, y, fmaf(6.0f, y, -3.0f)) : f8;
    f8 = (s == 10) ? 0.5f * (3.0f - y) * (3.0f - y) : f8;
    float z = tt - 9.0f;
    float f9 = 0.0f;
    f9 = (s == 9)  ? z : f9;
    f9 = (s == 10) ? 2.0f - z : f9;
    float f10 = (s == 10) ? 1.0f : 0.0f;
    *reinterpret_cast<uint2*>(g4half) = make_uint2(pk2(f8, f9), pk2(f10, xv));
}

// Pack B in DENSE per-(kstep,o) 64B units: Bp[kstep][o][e32] (same as R6-R15).
__global__ __launch_bounds__(256) void k_packB(const float* __restrict__ cp,
                                               const float* __restrict__ w,
                                               unsigned short* __restrict__ Bp) {
    int idx = blockIdx.x * 256 + threadIdx.x;
    if (idx >= COUT * KTOT) return;
    int kstep = idx >> 12;
    int rem   = idx & 4095;
    int o     = rem >> 5;
    int e32   = rem & 31;
    int ch = kstep / 27, sc = kstep - ch * 27;
    int ktap = sc / 3, ph = sc - ktap * 3;
    int c, n;
    if (ph < 2) { c = ch * 8 + ph * 4 + (e32 >> 3); n = e32 & 7; }
    else        { int sub = e32 & 7; c = ch * 8 + (e32 >> 3) * 2 + (sub >> 2); n = 8 + (sub & 3); }
    float v;
    if (n < 11) v = cp[(((size_t)o * CIN + c) * 9 + ktap) * 11 + n];
    else        v = w[((size_t)o * CIN + c) * 9 + ktap];
    Bp[idx] = f2bf(v);
}

// R15 kernel with ONE change: per-step order is now
//   vmcnt -> MFMA cluster -> aread(s+2) -> BLOAD refill
// so any conservative lgkmcnt the compiler emits before the MFMAs covers
// reads issued a full step earlier (no per-step LDS-latency stall).
__global__ __launch_bounds__(256) void k_main(const float* __restrict__ x,
                                              const unsigned short* __restrict__ Bp,
                                              float* __restrict__ out,
                                              float* __restrict__ part) {
    __shared__ char lds[2 * BUF_SIZE];

    const int bid  = blockIdx.x;
    // XCD swizzle: 392 = 8*49; one image per XCD -> x+B L2-resident.
    const int b    = bid & 7;
    const int tile = bid >> 3;            // 0..48
    const int th   = tile / 7;
    const int tw   = tile - th * 7;
    const int t    = threadIdx.x;
    const int lane = t & 63;
    const int wid  = t >> 6;              // 0..3 : o-quarter

    // ---- staging roles: 800 (pixel,channel) pairs per chunk, 4 slots/thread
    const bool valid = (t < 200);
    const int p     = (t < 100) ? t : (t - 100);
    const int hi100 = (t >= 100) ? 1 : 0;
    const int ph_  = p / 10, pw_ = p - ph_ * 10;
    const int hg = th * TH - 1 + ph_;
    const int wg = tw * TW - 1 + pw_;
    const bool inb = valid && (hg >= 0) && (hg < HW) && (wg >= 0) && (wg < HW);
    const u64 xadv = inb ? (u64)8 * L_ * 4 : 0;
    u64 px[4];
#pragma unroll
    for (int r = 0; r < 4; r++) {
        int c0 = 2 * r + hi100;
        px[r] = inb ? ((u64)x + (((u64)b * CIN + c0) * L_ + (u64)hg * HW + wg) * 4)
                    : (u64)x;
    }

    // ---- MFMA lane invariants ----
    const int q   = lane >> 4;
    const int r15 = lane & 15;
    int P[4];
#pragma unroll
    for (int mi = 0; mi < 4; mi++) {
        int lh = mi * 2 + (r15 >> 3);
        int lw = r15 & 7;
        P[mi] = (lh * HALO_W + lw) * 16 + q * CSTR;
    }
    const int obase = wid * 32 + r15;

    // B running pointers, dense layout; per-step stride 8192B, wrap at end.
    const u64 bend = (u64)Bp + BP_BYTES;
    u64 pa0 = (u64)Bp + ((u64)obase * 64) + ((u64)q * 16);
    u64 pa1 = pa0 + 1024;                 // +16 o

    f32x4 acc[4][2];
#pragma unroll
    for (int mi = 0; mi < 4; mi++)
#pragma unroll
        for (int ni = 0; ni < 2; ni++) acc[mi][ni] = (f32x4){0.f, 0.f, 0.f, 0.f};

    // ---- chunk-0 x loads + eval ----
    float xa[4];
    XLOAD(xa[0], px[0]); XLOAD(xa[1], px[1]);
    XLOAD(xa[2], px[2]); XLOAD(xa[3], px[3]);
#pragma unroll
    for (int r = 0; r < 4; r++) px[r] += xadv;   // -> chunk-1 channels
    asm volatile("s_waitcnt vmcnt(0)");
    __builtin_amdgcn_sched_barrier(0);
    if (valid) {
#pragma unroll
        for (int r = 0; r < 4; r++) {
            float va = inb ? xa[r] : 0.0f;
            int c = 2 * r + hi100;
            eval_store(va, &lds[c * CSTR + p * 16],
                       &lds[G8_SIZE + r * CSTR + p * 16 + hi100 * 8]);
        }
    }
    __syncthreads();

    // ---- B pipeline prologue: 9 pairs in flight ----
    bf16x8 breg0[9], breg1[9];
#pragma unroll
    for (int s = 0; s < 9; s++) {
        BLOAD(breg0[s], pa0);
        BLOAD(breg1[s], pa1);
        pa0 += 8192; pa1 += 8192;
    }

#pragma unroll 1
    for (int ch = 0; ch < 8; ch++) {
        // x quad for chunk ch+1 (ch==7: dummy reload of chunk-7, in bounds)
        XLOAD(xa[0], px[0]); XLOAD(xa[1], px[1]);
        XLOAD(xa[2], px[2]); XLOAD(xa[3], px[3]);
        if (ch < 6) {                      // keep px in bounds for dummy reload
#pragma unroll
            for (int r = 0; r < 4; r++) px[r] += xadv;
        }

        char* abuf = &lds[(ch & 1) * BUF_SIZE];
        char* nbuf = &lds[((ch + 1) & 1) * BUF_SIZE];

        bf16x8 areg[3][4];
        auto aread = [&](int s, bf16x8 (&a)[4]) {
            int k = s / 3, bp = s - k * 3;
            int ki = k / 3, kj = k - ki * 3;
            int poff = (ki * HALO_W + kj) * 16;
            int aoff = (bp == 2) ? (G8_SIZE + poff) : (bp * 4 * CSTR + poff);
#pragma unroll
            for (int mi = 0; mi < 4; mi++)
                a[mi] = *reinterpret_cast<const bf16x8*>(abuf + P[mi] + aoff);
        };
        aread(0, areg[0]);
        aread(1, areg[1]);

#pragma unroll
        for (int s = 0; s < 27; s++) {
            // Post-drain queue: outstanding = 4 + 2s (+prologue on ch==0);
            // vmcnt(16) always retires the consumed pair, and the x quad by
            // s==8 (before the eval below).
            asm volatile("s_waitcnt vmcnt(16)");
            __builtin_amdgcn_sched_barrier(0);
            const int bs = s % 9;
#pragma unroll
            for (int mi = 0; mi < 4; mi++) {
                acc[mi][0] = __builtin_amdgcn_mfma_f32_16x16x32_bf16(areg[s % 3][mi], breg0[bs], acc[mi][0], 0, 0, 0);
                acc[mi][1] = __builtin_amdgcn_mfma_f32_16x16x32_bf16(areg[s % 3][mi], breg1[bs], acc[mi][1], 0, 0, 0);
            }
            // prefetch AFTER the MFMAs: any lgkmcnt before next step's MFMAs
            // now covers reads issued a full step ago -> no LDS-latency stall.
            if (s + 2 < 27) aread(s + 2, areg[(s + 2) % 3]);
            // refill consumed slot (wraps past Bp end -> start; wrapped values
            // never consumed)
            BLOAD(breg0[bs], pa0);
            BLOAD(breg1[bs], pa1);
            pa0 += 8192; if (pa0 >= bend) pa0 -= BP_BYTES;
            pa1 += 8192; if (pa1 >= bend) pa1 -= BP_BYTES;
        }

        if (ch < 7 && valid) {
#pragma unroll
            for (int r = 0; r < 4; r++) {
                float va = inb ? xa[r] : 0.0f;
                int c = 2 * r + hi100;
                eval_store(va, &nbuf[c * CSTR + p * 16],
                           &nbuf[G8_SIZE + r * CSTR + p * 16 + hi100 * 8]);
            }
        }
        __syncthreads();   // full fence: drains vmem+lds, orders LDS reuse
    }

    // ---- epilogue: store + fused BN partial stats ----
    float psum[2] = {0.f, 0.f}, psq[2] = {0.f, 0.f};
#pragma unroll
    for (int ni = 0; ni < 2; ni++) {
        int o = obase + ni * 16;
#pragma unroll
        for (int mi = 0; mi < 4; mi++) {
            int lh = mi * 2 + (q >> 1);
            int lw0 = (q & 1) * 4;
            int lg = (th * TH + lh) * HW + tw * TW + lw0;
            float4 v;
            v.x = acc[mi][ni][0];
            v.y = acc[mi][ni][1];
            v.z = acc[mi][ni][2];
            v.w = acc[mi][ni][3];
            *reinterpret_cast<float4*>(&out[(size_t)(b * COUT + o) * L_ + lg]) = v;
            psum[ni] += v.x + v.y + v.z + v.w;
            psq[ni]  += v.x * v.x + v.y * v.y + v.z * v.z + v.w * v.w;
        }
    }
    // reduce across the 4 q-groups (lanes r15, r15+16, r15+32, r15+48 share o)
#pragma unroll
    for (int ni = 0; ni < 2; ni++) {
        psum[ni] += __shfl_xor(psum[ni], 16);
        psum[ni] += __shfl_xor(psum[ni], 32);
        psq[ni]  += __shfl_xor(psq[ni], 16);
        psq[ni]  += __shfl_xor(psq[ni], 32);
    }
    if (q == 0) {
#pragma unroll
        for (int ni = 0; ni < 2; ni++) {
            int o = obase + ni * 16;
            atomicAdd(&part[b * COUT + o], psum[ni]);
            atomicAdd(&part[1024 + b * COUT + o], psq[ni]);
        }
    }
}

__global__ __launch_bounds__(128) void k_final(const float* __restrict__ part,
                                               const float* __restrict__ gamma,
                                               const float* __restrict__ beta,
                                               float* __restrict__ ss) {
    int o = threadIdx.x;
    float sum = 0.f, sq = 0.f;
#pragma unroll
    for (int b = 0; b < 8; b++) {
        sum += part[b * COUT + o];
        sq  += part[1024 + b * COUT + o];
    }
    float n = (float)(8 * L_);
    float mean = sum / n;
    float var  = sq / n - mean * mean;
    float scale = gamma[o] * rsqrtf(var + 1e-5f);
    ss[o]        = scale;
    ss[COUT + o] = beta[o] - mean * scale;
}

__global__ __launch_bounds__(256) void k_norm(float* __restrict__ out,
                                              const float* __restrict__ ss) {
    const int n4 = 8 * COUT * L_ / 4;
    for (int i = blockIdx.x * 256 + threadIdx.x; i < n4; i += gridDim.x * 256) {
        int o = ((i * 4) / L_) & (COUT - 1);
        float sc = ss[o], sh = ss[COUT + o];
        float4 v = reinterpret_cast<float4*>(out)[i];
        v.x = fmaf(v.x, sc, sh);
        v.y = fmaf(v.y, sc, sh);
        v.z = fmaf(v.z, sc, sh);
        v.w = fmaf(v.w, sc, sh);
        reinterpret_cast<float4*>(out)[i] = v;
    }
}

extern "C" void kernel_launch(void* const* d_in, const int* in_sizes, int n_in,
                              void* d_out, int out_size, void* d_ws, size_t ws_size,
                              hipStream_t stream) {
    const float* x     = (const float*)d_in[0];
    const float* cp    = (const float*)d_in[1];
    const float* w     = (const float*)d_in[2];
    const float* gamma = (const float*)d_in[4];
    const float* beta  = (const float*)d_in[5];
    float* out = (float*)d_out;

    unsigned short* Bp = (unsigned short*)d_ws;
    float* part = (float*)((char*)d_ws + PART_OFF);
    float* ss   = (float*)((char*)d_ws + SS_OFF);

    hipMemsetAsync(part, 0, 2048 * sizeof(float), stream);
    k_packB<<<(COUT * KTOT + 255) / 256, 256, 0, stream>>>(cp, w, Bp);
    k_main<<<8 * 49, 256, 0, stream>>>(x, Bp, out, part);
    k_final<<<1, 128, 0, stream>>>(part, gamma, beta, ss);
    k_norm<<<2048, 256, 0, stream>>>(out, ss);
}